// Round 5
// baseline (477.628 us; speedup 1.0000x reference)
//
#include <hip/hip_runtime.h>

#define N_NODES 50000
#define N_EDGES 1600000
#define IN_F    512
#define OUT_F   256

// two-pass sort params: fine buckets of 128 rows
#define BROWS   128
#define NBINS   ((N_NODES + BROWS - 1) / BROWS)    // 391
#define BATCH   2048
#define NBATCHES ((N_EDGES + BATCH - 1) / BATCH)   // 782

// gather feature-sharding: 8 slices of 32 features, one slice per XCD L2
#define SLICES   8
#define SLICE_F  32
#define GROWS    32          // rows per gather block (4 waves x 8 groups)

typedef __attribute__((ext_vector_type(8))) short bf16x8;
typedef __attribute__((ext_vector_type(4))) float f32x4;

__device__ __forceinline__ short bf16rne(float f) {
    unsigned u = __builtin_bit_cast(unsigned, f);
    u += 0x7fffu + ((u >> 16) & 1u);          // round-to-nearest-even
    return (short)(u >> 16);
}

__device__ __forceinline__ float b2f(unsigned short h) {
    unsigned u = (unsigned)h << 16;
    return __builtin_bit_cast(float, u);
}

// ---------------------------------------------------------------------------
// Kernel 0: Wt[n][k] = bf16(W[k][n])  — transpose + convert weight (512x256)
// ---------------------------------------------------------------------------
__global__ __launch_bounds__(256) void wt_kernel(const float* __restrict__ W,
                                                 short* __restrict__ Wt) {
    int idx = blockIdx.x * 256 + threadIdx.x;
    if (idx < IN_F * OUT_F) {
        int n = idx >> 9;          // /512
        int k = idx & 511;
        Wt[idx] = bf16rne(W[(size_t)k * OUT_F + n]);
    }
}

// ---------------------------------------------------------------------------
// Kernel 1: support(bf16) = features @ weight via bf16 MFMA.
// BM=64, BN=256 (full N -> A read once), BK=32. 4 waves, wave owns 64 cols.
// Epilogue writes SLICED layout: Cb[(n>>5)*N_NODES*32 + row*32 + (n&31)]
// so the gather's per-XCD slice tables are contiguous (3.2 MB each).
// ---------------------------------------------------------------------------
#define ASTRIDE 40
#define BSTRIDE 40

__global__ __launch_bounds__(256) void gemm_mfma_kernel(const float* __restrict__ A,
                                                        const short* __restrict__ Wt,
                                                        unsigned short* __restrict__ Cb) {
    __shared__ short As[64 * ASTRIDE];
    __shared__ short Bs[256 * BSTRIDE];

    const int tid  = threadIdx.x;
    const int wave = tid >> 6;
    const int lane = tid & 63;
    const int m0   = blockIdx.x * 64;
    const int n0w  = wave * 64;

    const int quad = lane >> 4;
    const int l16  = lane & 15;

    const int ar = tid >> 2;
    const int aq = tid & 3;

    f32x4 zero4 = {0.f, 0.f, 0.f, 0.f};
    f32x4 acc[4][4];
#pragma unroll
    for (int i = 0; i < 4; ++i)
#pragma unroll
        for (int j = 0; j < 4; ++j) acc[i][j] = zero4;

    for (int k0 = 0; k0 < IN_F; k0 += 32) {
        {
            const int gm = m0 + ar;
            float4 v0 = make_float4(0.f, 0.f, 0.f, 0.f);
            float4 v1 = v0;
            if (gm < N_NODES) {
                const float* p = A + (size_t)gm * IN_F + k0 + aq * 8;
                v0 = *(const float4*)p;
                v1 = *(const float4*)(p + 4);
            }
            bf16x8 b;
            b[0] = bf16rne(v0.x); b[1] = bf16rne(v0.y);
            b[2] = bf16rne(v0.z); b[3] = bf16rne(v0.w);
            b[4] = bf16rne(v1.x); b[5] = bf16rne(v1.y);
            b[6] = bf16rne(v1.z); b[7] = bf16rne(v1.w);
            *(bf16x8*)&As[ar * ASTRIDE + aq * 8] = b;
        }
        {
            const short* src = Wt + (size_t)tid * IN_F + k0;
            bf16x8 w0 = *(const bf16x8*)(src + 0);
            bf16x8 w1 = *(const bf16x8*)(src + 8);
            bf16x8 w2 = *(const bf16x8*)(src + 16);
            bf16x8 w3 = *(const bf16x8*)(src + 24);
            short* dst = &Bs[tid * BSTRIDE];
            *(bf16x8*)(dst + 0)  = w0;
            *(bf16x8*)(dst + 8)  = w1;
            *(bf16x8*)(dst + 16) = w2;
            *(bf16x8*)(dst + 24) = w3;
        }
        __syncthreads();

        bf16x8 af[4], bf[4];
#pragma unroll
        for (int mt = 0; mt < 4; ++mt)
            af[mt] = *(const bf16x8*)&As[(mt * 16 + l16) * ASTRIDE + quad * 8];
#pragma unroll
        for (int nt = 0; nt < 4; ++nt)
            bf[nt] = *(const bf16x8*)&Bs[(n0w + nt * 16 + l16) * BSTRIDE + quad * 8];

#pragma unroll
        for (int mt = 0; mt < 4; ++mt)
#pragma unroll
            for (int nt = 0; nt < 4; ++nt)
                acc[mt][nt] = __builtin_amdgcn_mfma_f32_16x16x32_bf16(
                    af[mt], bf[nt], acc[mt][nt], 0, 0, 0);
        __syncthreads();
    }

#pragma unroll
    for (int mt = 0; mt < 4; ++mt) {
        const int rbase = m0 + mt * 16 + quad * 4;
#pragma unroll
        for (int i = 0; i < 4; ++i) {
            const int row = rbase + i;
            if (row < N_NODES) {
#pragma unroll
                for (int nt = 0; nt < 4; ++nt) {
                    const int n  = n0w + nt * 16 + l16;
                    const int sl = n >> 5;
                    const int wi = n & 31;
                    Cb[((size_t)sl * N_NODES + row) * SLICE_F + wi] =
                        (unsigned short)bf16rne(acc[mt][nt][i]);
                }
            }
        }
    }
}

// ---------------------------------------------------------------------------
// Two-pass edge sort (391 buckets x 128 rows).
// Pass A: coarse bin by row>>7, LDS-staged for contiguous bucket runs.
//         binned entry: x = (row&127)<<16 | col, y = fp32 val bits.
// Pass B: per-bucket counting sort over 128 local rows; emits global excl and
//         packed 4B edge records: (col<<16) | bf16(val).
// ---------------------------------------------------------------------------
__global__ __launch_bounds__(256) void zero_bins_kernel(int* __restrict__ binCounts) {
    int i = blockIdx.x * 256 + threadIdx.x;
    if (i < NBINS) binCounts[i] = 0;
}

__global__ __launch_bounds__(256) void histA_kernel(const int* __restrict__ rows,
                                                    int* __restrict__ binCounts) {
    __shared__ int lh[NBINS];
    const int tid = threadIdx.x;
    for (int i = tid; i < NBINS; i += 256) lh[i] = 0;
    __syncthreads();
    for (int i = blockIdx.x * 256 + tid; i < N_EDGES; i += gridDim.x * 256)
        atomicAdd(&lh[rows[i] >> 7], 1);
    __syncthreads();
    for (int i = tid; i < NBINS; i += 256)
        if (lh[i]) atomicAdd(&binCounts[i], lh[i]);
}

// exclusive scan of 391 bin counts (pair-scan, 512 padded, 256 threads)
__global__ __launch_bounds__(256) void scanA_kernel(const int* __restrict__ binCounts,
                                                    int* __restrict__ binStart,
                                                    int* __restrict__ gcursor) {
    __shared__ int stmp[256];
    const int tid = threadIdx.x;
    const int i0 = 2 * tid, i1 = 2 * tid + 1;
    const int a0 = (i0 < NBINS) ? binCounts[i0] : 0;
    const int a1 = (i1 < NBINS) ? binCounts[i1] : 0;
    const int pair = a0 + a1;
    stmp[tid] = pair;
    for (int off = 1; off < 256; off <<= 1) {
        __syncthreads();
        int t = (tid >= off) ? stmp[tid - off] : 0;
        __syncthreads();
        stmp[tid] += t;
    }
    __syncthreads();
    const int pexcl = stmp[tid] - pair;
    if (i0 < NBINS) { binStart[i0] = pexcl;      gcursor[i0] = pexcl; }
    if (i1 < NBINS) { binStart[i1] = pexcl + a0; gcursor[i1] = pexcl + a0; }
}

__global__ __launch_bounds__(256) void fillA_kernel(const int* __restrict__ rows,
                                                    const int* __restrict__ cols,
                                                    const float* __restrict__ vals,
                                                    int* __restrict__ gcursor,
                                                    int2* __restrict__ binned) {
    __shared__ int lhist[NBINS];
    __shared__ int lexcl[NBINS];
    __shared__ int gbase[NBINS];
    __shared__ int stmp[256];
    __shared__ int2 lstage[BATCH];
    __shared__ unsigned short sbucket[BATCH];

    const int tid   = threadIdx.x;
    const int start = blockIdx.x * BATCH;
    const int count = min(BATCH, N_EDGES - start);

    for (int i = tid; i < NBINS; i += 256) lhist[i] = 0;
    __syncthreads();

    int myrow[8], myrank[8];
#pragma unroll
    for (int j = 0; j < 8; ++j) {
        const int s = j * 256 + tid;
        if (s < count) {
            const int r = rows[start + s];
            myrow[j]  = r;
            myrank[j] = atomicAdd(&lhist[r >> 7], 1);
        }
    }
    __syncthreads();

    // pair-scan of lhist (391 -> 512 padded) + reserve global space per bucket
    {
        const int i0 = 2 * tid, i1 = 2 * tid + 1;
        const int a0 = (i0 < NBINS) ? lhist[i0] : 0;
        const int a1 = (i1 < NBINS) ? lhist[i1] : 0;
        const int pair = a0 + a1;
        stmp[tid] = pair;
        for (int off = 1; off < 256; off <<= 1) {
            __syncthreads();
            int t = (tid >= off) ? stmp[tid - off] : 0;
            __syncthreads();
            stmp[tid] += t;
        }
        __syncthreads();
        const int pexcl = stmp[tid] - pair;
        if (i0 < NBINS) {
            lexcl[i0] = pexcl;
            gbase[i0] = a0 ? atomicAdd(&gcursor[i0], a0) : 0;
        }
        if (i1 < NBINS) {
            lexcl[i1] = pexcl + a0;
            gbase[i1] = a1 ? atomicAdd(&gcursor[i1], a1) : 0;
        }
    }
    __syncthreads();

    // stage into LDS ordered by bucket
#pragma unroll
    for (int j = 0; j < 8; ++j) {
        const int s = j * 256 + tid;
        if (s < count) {
            const int r   = myrow[j];
            const int b   = r >> 7;
            const int pos = lexcl[b] + myrank[j];
            lstage[pos]  = make_int2(((r & 127) << 16) | cols[start + s],
                                     __float_as_int(vals[start + s]));
            sbucket[pos] = (unsigned short)b;
        }
    }
    __syncthreads();

    // write out: bucket runs contiguous
#pragma unroll
    for (int j = 0; j < 8; ++j) {
        const int s = j * 256 + tid;
        if (s < count) {
            const int b = sbucket[s];
            binned[gbase[b] + (s - lexcl[b])] = lstage[s];
        }
    }
}

__global__ __launch_bounds__(256) void sortB_kernel(const int2* __restrict__ binned,
                                                    const int* __restrict__ binStart,
                                                    const int* __restrict__ binCounts,
                                                    int* __restrict__ excl,
                                                    unsigned int* __restrict__ ecv) {
    __shared__ int lhist[BROWS];
    __shared__ int lcur[BROWS];

    const int tid  = threadIdx.x;
    const int b    = blockIdx.x;
    const int base = binStart[b];
    const int cnt  = binCounts[b];

    if (tid < BROWS) lhist[tid] = 0;
    __syncthreads();

    for (int i = tid; i < cnt; i += 256)
        atomicAdd(&lhist[binned[base + i].x >> 16], 1);
    __syncthreads();

    // scan 128 with first 128 threads (Hillis-Steele in lcur as temp)
    if (tid < BROWS) lcur[tid] = lhist[tid];
    for (int off = 1; off < BROWS; off <<= 1) {
        __syncthreads();
        int t = (tid >= off && tid < BROWS) ? lcur[tid - off] : 0;
        __syncthreads();
        if (tid < BROWS) lcur[tid] += t;
    }
    __syncthreads();
    if (tid < BROWS) {
        const int pexcl = lcur[tid] - lhist[tid];
        const int row   = b * BROWS + tid;
        lcur[tid] = pexcl;
        if (row < N_NODES) excl[row] = base + pexcl;
    }
    __syncthreads();

    for (int i = tid; i < cnt; i += 256) {
        const int2 e  = binned[base + i];
        const int rl  = e.x >> 16;
        const int col = e.x & 0xFFFF;
        const int rank = atomicAdd(&lcur[rl], 1);
        ecv[base + rank] = ((unsigned int)col << 16) |
                           (unsigned short)bf16rne(__int_as_float(e.y));
    }
}

// ---------------------------------------------------------------------------
// Gather, XCD-sharded by feature slice + one 8-lane group per row.
// blockIdx%8 = slice -> round-robin XCD mapping pins each 3.2 MB support
// slice into one XCD's 4 MB L2 (R4 counters: FETCH 352->55 MB, confirmed).
// Each wave = 8 groups x 8 lanes; group owns one row, lane owns 4 features
// of the 32-feature slice -> no cross-lane reduction. Edge loop 8-deep
// software-pipelined: 8 support loads + 8 prefetched ecv records in flight
// per lane (ecv reads are group-uniform -> HW broadcast). Fused ReLU.
// ---------------------------------------------------------------------------
__global__ __launch_bounds__(256) void gather_kernel(const ushort4* __restrict__ support,
                                                     const int* __restrict__ excl,
                                                     const unsigned int* __restrict__ ecv,
                                                     float* __restrict__ out) {
    const int tid   = threadIdx.x;
    const int slice = blockIdx.x & 7;
    const int rg    = blockIdx.x >> 3;
    const int wave  = tid >> 6;
    const int lane  = tid & 63;
    const int g     = lane >> 3;     // group 0..7, one row each
    const int f     = lane & 7;      // ushort4 index within 64B row-slice

    const ushort4* sup = support + (size_t)slice * N_NODES * 8;
    const int row   = rg * GROWS + wave * 8 + g;
    const bool valid = row < N_NODES;

    int start = 0, end = 0;
    if (valid) {
        start = excl[row];
        end   = (row + 1 < N_NODES) ? excl[row + 1] : N_EDGES;
    }

    f32x4 acc = {0.f, 0.f, 0.f, 0.f};

    // prime the 8-record pipeline (p==0 -> col 0, val +0.0 -> contributes 0)
    unsigned pc[8];
#pragma unroll
    for (int j = 0; j < 8; ++j)
        pc[j] = (start + j < end) ? __builtin_nontemporal_load(&ecv[start + j]) : 0u;

    for (int e = start; e < end; e += 8) {
        // 8 support loads in flight per lane
        ushort4 s[8];
#pragma unroll
        for (int j = 0; j < 8; ++j)
            s[j] = sup[(size_t)(pc[j] >> 16) * 8 + f];

        // prefetch next 8 edge records while support loads fly
        unsigned pn[8];
#pragma unroll
        for (int j = 0; j < 8; ++j) {
            const int i1 = e + 8 + j;
            pn[j] = (i1 < end) ? __builtin_nontemporal_load(&ecv[i1]) : 0u;
        }

#pragma unroll
        for (int j = 0; j < 8; ++j) {
            const float v = b2f((unsigned short)(pc[j] & 0xFFFF));
            acc[0] += v * b2f(s[j].x);
            acc[1] += v * b2f(s[j].y);
            acc[2] += v * b2f(s[j].z);
            acc[3] += v * b2f(s[j].w);
        }
#pragma unroll
        for (int j = 0; j < 8; ++j) pc[j] = pn[j];
    }

    if (valid) {
        f32x4 r;
        r[0] = fmaxf(acc[0], 0.f);
        r[1] = fmaxf(acc[1], 0.f);
        r[2] = fmaxf(acc[2], 0.f);
        r[3] = fmaxf(acc[3], 0.f);
        __builtin_nontemporal_store(
            r, (f32x4*)(out + (size_t)row * OUT_F + slice * SLICE_F + f * 4));
    }
}

extern "C" void kernel_launch(void* const* d_in, const int* in_sizes, int n_in,
                              void* d_out, int out_size, void* d_ws, size_t ws_size,
                              hipStream_t stream) {
    const float* features  = (const float*)d_in[0];   // [50000, 512]
    const float* weight    = (const float*)d_in[1];   // [512, 256]
    const float* edge_vals = (const float*)d_in[2];   // [1.6M]
    const int*   edge_rows = (const int*)d_in[3];
    const int*   edge_cols = (const int*)d_in[4];
    float* out = (float*)d_out;                       // [50000, 256]

    // workspace layout (8B-aligned chunks first)
    unsigned short* support_bf = (unsigned short*)d_ws;                 // 25.6 MB (sliced)
    int2*  binned    = (int2*)(support_bf + (size_t)N_NODES * OUT_F);   // 12.8 MB
    unsigned int* ecv = (unsigned int*)(binned + N_EDGES);              // 6.4 MB
    int*   excl      = (int*)(ecv + N_EDGES);                           // 50000
    int*   binCounts = excl + N_NODES;                                  // 512
    int*   binStart  = binCounts + 512;                                 // 512
    int*   gcursor   = binStart + 512;                                  // 512
    short* Wt        = (short*)(gcursor + 512);                         // 131072 bf16

    // 1) weight transpose + bf16 convert
    wt_kernel<<<(IN_F * OUT_F + 255) / 256, 256, 0, stream>>>(weight, Wt);

    // 2) MFMA GEMM: support(bf16, sliced layout) = features @ weight
    gemm_mfma_kernel<<<(N_NODES + 63) / 64, 256, 0, stream>>>(features, Wt, support_bf);

    // 3) two-pass edge sort
    zero_bins_kernel<<<2, 256, 0, stream>>>(binCounts);
    histA_kernel<<<256, 256, 0, stream>>>(edge_rows, binCounts);
    scanA_kernel<<<1, 256, 0, stream>>>(binCounts, binStart, gcursor);
    fillA_kernel<<<NBATCHES, 256, 0, stream>>>(edge_rows, edge_cols, edge_vals,
                                               gcursor, binned);
    sortB_kernel<<<NBINS, 256, 0, stream>>>(binned, binStart, binCounts, excl, ecv);

    // 4) gather + fused ReLU, XCD-sharded by feature slice, group-per-row
    const int nrg = (N_NODES + GROWS - 1) / GROWS;   // 1563
    gather_kernel<<<nrg * SLICES, 256, 0, stream>>>(
        (const ushort4*)support_bf, excl, ecv, (float*)out);
}

// Round 6
// 372.977 us; speedup vs baseline: 1.2806x; 1.2806x over previous
//
#include <hip/hip_runtime.h>

#define N_NODES 50000
#define N_EDGES 1600000
#define IN_F    512
#define OUT_F   256

// two-pass sort params: fine buckets of 128 rows
#define BROWS   128
#define NBINS   ((N_NODES + BROWS - 1) / BROWS)    // 391
#define BATCH   2048
#define NBATCHES ((N_EDGES + BATCH - 1) / BATCH)   // 782

typedef __attribute__((ext_vector_type(8))) short bf16x8;
typedef __attribute__((ext_vector_type(4))) float f32x4;

__device__ __forceinline__ short bf16rne(float f) {
    unsigned u = __builtin_bit_cast(unsigned, f);
    u += 0x7fffu + ((u >> 16) & 1u);          // round-to-nearest-even
    return (short)(u >> 16);
}

__device__ __forceinline__ float b2f(unsigned short h) {
    unsigned u = (unsigned)h << 16;
    return __builtin_bit_cast(float, u);
}

// ---------------------------------------------------------------------------
// Kernel 0: Wt[n][k] = bf16(W[k][n])  — transpose + convert weight (512x256)
// ---------------------------------------------------------------------------
__global__ __launch_bounds__(256) void wt_kernel(const float* __restrict__ W,
                                                 short* __restrict__ Wt) {
    int idx = blockIdx.x * 256 + threadIdx.x;
    if (idx < IN_F * OUT_F) {
        int n = idx >> 9;          // /512
        int k = idx & 511;
        Wt[idx] = bf16rne(W[(size_t)k * OUT_F + n]);
    }
}

// ---------------------------------------------------------------------------
// Kernel 1: support(bf16) = features @ weight via bf16 MFMA.
// BM=128, BN=256 (full N), BK=32. 8 waves (512 thr): wave-tile 64x64.
// vs BM=64: halves B-panel re-staging traffic (782->391 blocks x 256KB)
// at identical per-wave acc footprint (4x4 f32x4).
// ---------------------------------------------------------------------------
#define ASTRIDE 40
#define BSTRIDE 40

__global__ __launch_bounds__(512) void gemm_mfma_kernel(const float* __restrict__ A,
                                                        const short* __restrict__ Wt,
                                                        unsigned short* __restrict__ Cb) {
    __shared__ short As[128 * ASTRIDE];
    __shared__ short Bs[256 * BSTRIDE];

    const int tid  = threadIdx.x;
    const int wave = tid >> 6;
    const int lane = tid & 63;
    const int m0   = blockIdx.x * 128;
    const int wrow = (wave >> 2) * 64;       // 0 or 64
    const int wcol = (wave & 3) * 64;        // 0/64/128/192

    const int quad = lane >> 4;
    const int l16  = lane & 15;

    const int ar = tid >> 2;                 // 0..127 (A row within tile)
    const int aq = tid & 3;                  // 0..3   (8-wide k chunk)

    const int bn = tid >> 1;                 // 0..255 (B row = out col)
    const int bh = tid & 1;                  // 0..1   (16-wide k half)

    f32x4 zero4 = {0.f, 0.f, 0.f, 0.f};
    f32x4 acc[4][4];
#pragma unroll
    for (int i = 0; i < 4; ++i)
#pragma unroll
        for (int j = 0; j < 4; ++j) acc[i][j] = zero4;

    for (int k0 = 0; k0 < IN_F; k0 += 32) {
        {
            const int gm = m0 + ar;
            float4 v0 = make_float4(0.f, 0.f, 0.f, 0.f);
            float4 v1 = v0;
            if (gm < N_NODES) {
                const float* p = A + (size_t)gm * IN_F + k0 + aq * 8;
                v0 = *(const float4*)p;
                v1 = *(const float4*)(p + 4);
            }
            bf16x8 b;
            b[0] = bf16rne(v0.x); b[1] = bf16rne(v0.y);
            b[2] = bf16rne(v0.z); b[3] = bf16rne(v0.w);
            b[4] = bf16rne(v1.x); b[5] = bf16rne(v1.y);
            b[6] = bf16rne(v1.z); b[7] = bf16rne(v1.w);
            *(bf16x8*)&As[ar * ASTRIDE + aq * 8] = b;
        }
        {
            const short* src = Wt + (size_t)bn * IN_F + k0 + bh * 16;
            bf16x8 w0 = *(const bf16x8*)(src + 0);
            bf16x8 w1 = *(const bf16x8*)(src + 8);
            short* dst = &Bs[bn * BSTRIDE + bh * 16];
            *(bf16x8*)(dst + 0) = w0;
            *(bf16x8*)(dst + 8) = w1;
        }
        __syncthreads();

        bf16x8 af[4], bf[4];
#pragma unroll
        for (int mt = 0; mt < 4; ++mt)
            af[mt] = *(const bf16x8*)&As[(wrow + mt * 16 + l16) * ASTRIDE + quad * 8];
#pragma unroll
        for (int nt = 0; nt < 4; ++nt)
            bf[nt] = *(const bf16x8*)&Bs[(wcol + nt * 16 + l16) * BSTRIDE + quad * 8];

#pragma unroll
        for (int mt = 0; mt < 4; ++mt)
#pragma unroll
            for (int nt = 0; nt < 4; ++nt)
                acc[mt][nt] = __builtin_amdgcn_mfma_f32_16x16x32_bf16(
                    af[mt], bf[nt], acc[mt][nt], 0, 0, 0);
        __syncthreads();
    }

#pragma unroll
    for (int mt = 0; mt < 4; ++mt) {
        const int rbase = m0 + wrow + mt * 16 + quad * 4;
#pragma unroll
        for (int i = 0; i < 4; ++i) {
            const int row = rbase + i;
            if (row < N_NODES) {
#pragma unroll
                for (int nt = 0; nt < 4; ++nt)
                    Cb[(size_t)row * OUT_F + wcol + nt * 16 + l16] =
                        (unsigned short)bf16rne(acc[mt][nt][i]);
            }
        }
    }
}

// ---------------------------------------------------------------------------
// Two-pass edge sort (391 buckets x 128 rows).
// Pass A: coarse bin by row>>7, LDS-staged for contiguous bucket runs.
//         binned entry: x = (row&127)<<16 | col, y = fp32 val bits.
// Pass B: per-bucket counting sort over 128 local rows; emits global excl and
//         packed 4B edge records: (col<<16) | bf16(val).
// ---------------------------------------------------------------------------
__global__ __launch_bounds__(256) void zero_bins_kernel(int* __restrict__ binCounts) {
    int i = blockIdx.x * 256 + threadIdx.x;
    if (i < NBINS) binCounts[i] = 0;
}

__global__ __launch_bounds__(256) void histA_kernel(const int* __restrict__ rows,
                                                    int* __restrict__ binCounts) {
    __shared__ int lh[NBINS];
    const int tid = threadIdx.x;
    for (int i = tid; i < NBINS; i += 256) lh[i] = 0;
    __syncthreads();
    for (int i = blockIdx.x * 256 + tid; i < N_EDGES; i += gridDim.x * 256)
        atomicAdd(&lh[rows[i] >> 7], 1);
    __syncthreads();
    for (int i = tid; i < NBINS; i += 256)
        if (lh[i]) atomicAdd(&binCounts[i], lh[i]);
}

// exclusive scan of 391 bin counts (pair-scan, 512 padded, 256 threads)
__global__ __launch_bounds__(256) void scanA_kernel(const int* __restrict__ binCounts,
                                                    int* __restrict__ binStart,
                                                    int* __restrict__ gcursor) {
    __shared__ int stmp[256];
    const int tid = threadIdx.x;
    const int i0 = 2 * tid, i1 = 2 * tid + 1;
    const int a0 = (i0 < NBINS) ? binCounts[i0] : 0;
    const int a1 = (i1 < NBINS) ? binCounts[i1] : 0;
    const int pair = a0 + a1;
    stmp[tid] = pair;
    for (int off = 1; off < 256; off <<= 1) {
        __syncthreads();
        int t = (tid >= off) ? stmp[tid - off] : 0;
        __syncthreads();
        stmp[tid] += t;
    }
    __syncthreads();
    const int pexcl = stmp[tid] - pair;
    if (i0 < NBINS) { binStart[i0] = pexcl;      gcursor[i0] = pexcl; }
    if (i1 < NBINS) { binStart[i1] = pexcl + a0; gcursor[i1] = pexcl + a0; }
}

__global__ __launch_bounds__(256) void fillA_kernel(const int* __restrict__ rows,
                                                    const int* __restrict__ cols,
                                                    const float* __restrict__ vals,
                                                    int* __restrict__ gcursor,
                                                    int2* __restrict__ binned) {
    __shared__ int lhist[NBINS];
    __shared__ int lexcl[NBINS];
    __shared__ int gbase[NBINS];
    __shared__ int stmp[256];
    __shared__ int2 lstage[BATCH];
    __shared__ unsigned short sbucket[BATCH];

    const int tid   = threadIdx.x;
    const int start = blockIdx.x * BATCH;
    const int count = min(BATCH, N_EDGES - start);

    for (int i = tid; i < NBINS; i += 256) lhist[i] = 0;
    __syncthreads();

    int myrow[8], myrank[8];
#pragma unroll
    for (int j = 0; j < 8; ++j) {
        const int s = j * 256 + tid;
        if (s < count) {
            const int r = rows[start + s];
            myrow[j]  = r;
            myrank[j] = atomicAdd(&lhist[r >> 7], 1);
        }
    }
    __syncthreads();

    // pair-scan of lhist (391 -> 512 padded) + reserve global space per bucket
    {
        const int i0 = 2 * tid, i1 = 2 * tid + 1;
        const int a0 = (i0 < NBINS) ? lhist[i0] : 0;
        const int a1 = (i1 < NBINS) ? lhist[i1] : 0;
        const int pair = a0 + a1;
        stmp[tid] = pair;
        for (int off = 1; off < 256; off <<= 1) {
            __syncthreads();
            int t = (tid >= off) ? stmp[tid - off] : 0;
            __syncthreads();
            stmp[tid] += t;
        }
        __syncthreads();
        const int pexcl = stmp[tid] - pair;
        if (i0 < NBINS) {
            lexcl[i0] = pexcl;
            gbase[i0] = a0 ? atomicAdd(&gcursor[i0], a0) : 0;
        }
        if (i1 < NBINS) {
            lexcl[i1] = pexcl + a0;
            gbase[i1] = a1 ? atomicAdd(&gcursor[i1], a1) : 0;
        }
    }
    __syncthreads();

    // stage into LDS ordered by bucket
#pragma unroll
    for (int j = 0; j < 8; ++j) {
        const int s = j * 256 + tid;
        if (s < count) {
            const int r   = myrow[j];
            const int b   = r >> 7;
            const int pos = lexcl[b] + myrank[j];
            lstage[pos]  = make_int2(((r & 127) << 16) | cols[start + s],
                                     __float_as_int(vals[start + s]));
            sbucket[pos] = (unsigned short)b;
        }
    }
    __syncthreads();

    // write out: bucket runs contiguous
#pragma unroll
    for (int j = 0; j < 8; ++j) {
        const int s = j * 256 + tid;
        if (s < count) {
            const int b = sbucket[s];
            binned[gbase[b] + (s - lexcl[b])] = lstage[s];
        }
    }
}

__global__ __launch_bounds__(256) void sortB_kernel(const int2* __restrict__ binned,
                                                    const int* __restrict__ binStart,
                                                    const int* __restrict__ binCounts,
                                                    int* __restrict__ excl,
                                                    unsigned int* __restrict__ ecv) {
    __shared__ int lhist[BROWS];
    __shared__ int lcur[BROWS];

    const int tid  = threadIdx.x;
    const int b    = blockIdx.x;
    const int base = binStart[b];
    const int cnt  = binCounts[b];

    if (tid < BROWS) lhist[tid] = 0;
    __syncthreads();

    for (int i = tid; i < cnt; i += 256)
        atomicAdd(&lhist[binned[base + i].x >> 16], 1);
    __syncthreads();

    // scan 128 with first 128 threads (Hillis-Steele in lcur as temp)
    if (tid < BROWS) lcur[tid] = lhist[tid];
    for (int off = 1; off < BROWS; off <<= 1) {
        __syncthreads();
        int t = (tid >= off && tid < BROWS) ? lcur[tid - off] : 0;
        __syncthreads();
        if (tid < BROWS) lcur[tid] += t;
    }
    __syncthreads();
    if (tid < BROWS) {
        const int pexcl = lcur[tid] - lhist[tid];
        const int row   = b * BROWS + tid;
        lcur[tid] = pexcl;
        if (row < N_NODES) excl[row] = base + pexcl;
    }
    __syncthreads();

    for (int i = tid; i < cnt; i += 256) {
        const int2 e  = binned[base + i];
        const int rl  = e.x >> 16;
        const int col = e.x & 0xFFFF;
        const int rank = atomicAdd(&lcur[rl], 1);
        ecv[base + rank] = ((unsigned int)col << 16) |
                           (unsigned short)bf16rne(__int_as_float(e.y));
    }
}

// ---------------------------------------------------------------------------
// Gather (R0 structure, best measured: ~105 us for full 50K rows).
// One wave per output row, support bf16 (ushort4/lane -> 512B/edge = 4 lines),
// packed 4B edge records, 4-edge unroll, fp32 accumulate, fused ReLU.
// row0 param: launched twice (25K rows each) for rocprof visibility of the
// non-gather kernels; total work identical.
// ---------------------------------------------------------------------------
__global__ __launch_bounds__(256) void gather_kernel(const ushort4* __restrict__ support,
                                                     const int* __restrict__ excl,
                                                     const unsigned int* __restrict__ ecv,
                                                     float4* __restrict__ out,
                                                     int row0) {
    const int tid  = threadIdx.x;
    const int row  = row0 + blockIdx.x * 4 + (tid >> 6);
    const int lane = tid & 63;
    if (row >= N_NODES) return;

    const int start = excl[row];
    const int end   = (row + 1 < N_NODES) ? excl[row + 1] : N_EDGES;

    float4 acc = make_float4(0.f, 0.f, 0.f, 0.f);
    int e = start;
    const int end4 = start + ((end - start) & ~3);
    for (; e < end4; e += 4) {
        const unsigned int p0 = ecv[e];
        const unsigned int p1 = ecv[e + 1];
        const unsigned int p2 = ecv[e + 2];
        const unsigned int p3 = ecv[e + 3];
        const ushort4 s0 = support[(size_t)(p0 >> 16) * 64 + lane];
        const ushort4 s1 = support[(size_t)(p1 >> 16) * 64 + lane];
        const ushort4 s2 = support[(size_t)(p2 >> 16) * 64 + lane];
        const ushort4 s3 = support[(size_t)(p3 >> 16) * 64 + lane];
        const float v0 = b2f((unsigned short)(p0 & 0xFFFF));
        const float v1 = b2f((unsigned short)(p1 & 0xFFFF));
        const float v2 = b2f((unsigned short)(p2 & 0xFFFF));
        const float v3 = b2f((unsigned short)(p3 & 0xFFFF));
        acc.x += v0 * b2f(s0.x); acc.y += v0 * b2f(s0.y);
        acc.z += v0 * b2f(s0.z); acc.w += v0 * b2f(s0.w);
        acc.x += v1 * b2f(s1.x); acc.y += v1 * b2f(s1.y);
        acc.z += v1 * b2f(s1.z); acc.w += v1 * b2f(s1.w);
        acc.x += v2 * b2f(s2.x); acc.y += v2 * b2f(s2.y);
        acc.z += v2 * b2f(s2.z); acc.w += v2 * b2f(s2.w);
        acc.x += v3 * b2f(s3.x); acc.y += v3 * b2f(s3.y);
        acc.z += v3 * b2f(s3.z); acc.w += v3 * b2f(s3.w);
    }
    for (; e < end; ++e) {
        const unsigned int p0 = ecv[e];
        const ushort4 s0 = support[(size_t)(p0 >> 16) * 64 + lane];
        const float v0 = b2f((unsigned short)(p0 & 0xFFFF));
        acc.x += v0 * b2f(s0.x); acc.y += v0 * b2f(s0.y);
        acc.z += v0 * b2f(s0.z); acc.w += v0 * b2f(s0.w);
    }

    acc.x = fmaxf(acc.x, 0.f);
    acc.y = fmaxf(acc.y, 0.f);
    acc.z = fmaxf(acc.z, 0.f);
    acc.w = fmaxf(acc.w, 0.f);
    out[(size_t)row * 64 + lane] = acc;
}

extern "C" void kernel_launch(void* const* d_in, const int* in_sizes, int n_in,
                              void* d_out, int out_size, void* d_ws, size_t ws_size,
                              hipStream_t stream) {
    const float* features  = (const float*)d_in[0];   // [50000, 512]
    const float* weight    = (const float*)d_in[1];   // [512, 256]
    const float* edge_vals = (const float*)d_in[2];   // [1.6M]
    const int*   edge_rows = (const int*)d_in[3];
    const int*   edge_cols = (const int*)d_in[4];
    float* out = (float*)d_out;                       // [50000, 256]

    // workspace layout (8B-aligned chunks first)
    unsigned short* support_bf = (unsigned short*)d_ws;                 // 25.6 MB
    int2*  binned    = (int2*)(support_bf + (size_t)N_NODES * OUT_F);   // 12.8 MB
    unsigned int* ecv = (unsigned int*)(binned + N_EDGES);              // 6.4 MB
    int*   excl      = (int*)(ecv + N_EDGES);                           // 50000
    int*   binCounts = excl + N_NODES;                                  // 512
    int*   binStart  = binCounts + 512;                                 // 512
    int*   gcursor   = binStart + 512;                                  // 512
    short* Wt        = (short*)(gcursor + 512);                         // 131072 bf16

    // 1) weight transpose + bf16 convert
    wt_kernel<<<(IN_F * OUT_F + 255) / 256, 256, 0, stream>>>(weight, Wt);

    // 2) MFMA GEMM: support(bf16) = features @ weight (BM=128, 8 waves)
    gemm_mfma_kernel<<<(N_NODES + 127) / 128, 512, 0, stream>>>(features, Wt, support_bf);

    // 3) two-pass edge sort
    zero_bins_kernel<<<2, 256, 0, stream>>>(binCounts);
    histA_kernel<<<256, 256, 0, stream>>>(edge_rows, binCounts);
    scanA_kernel<<<1, 256, 0, stream>>>(binCounts, binStart, gcursor);
    fillA_kernel<<<NBATCHES, 256, 0, stream>>>(edge_rows, edge_cols, edge_vals,
                                               gcursor, binned);
    sortB_kernel<<<NBINS, 256, 0, stream>>>(binned, binStart, binCounts, excl, ecv);

    // 4) gather + fused ReLU (one wave per row), split into 2 dispatches
    gather_kernel<<<25000 / 4, 256, 0, stream>>>(
        (const ushort4*)support_bf, excl, ecv, (float4*)out, 0);
    gather_kernel<<<25000 / 4, 256, 0, stream>>>(
        (const ushort4*)support_bf, excl, ecv, (float4*)out, 25000);
}